// Round 9
// baseline (427.748 us; speedup 1.0000x reference)
//
#include <hip/hip_runtime.h>

#define D_DIM 2048
#define E_NUM 64
#define M_TOK 16384          // B*L = 4*4096
#define BK 32                // k per staged tile
#define XS_ROW 36            // 32 + 4 pad: 144B rows keep 16B alignment for b128
#define XS_TILE (64 * XS_ROW)   // 2304 floats per (half, buf)
#define LDS_FLOATS 20736     // 82944 B > 160KiB/2: forces 1 block/CU (see below)

// ws layout: gprob[64], gcnt[64], Wt[2048*64] (f32, [k][e])

// one-off transpose W[e][k] -> Wt[k][e]; block 0 also zeroes gprob/gcnt
__global__ __launch_bounds__(256) void wt_kernel(const float* __restrict__ W,
                                                 float* __restrict__ Wt,
                                                 float* __restrict__ g) {
    if (blockIdx.x == 0 && threadIdx.x < 128) g[threadIdx.x] = 0.0f;
    const int i4 = blockIdx.x * 256 + threadIdx.x;   // grid 128 -> 32768 float4s
    const int e  = i4 >> 9;                          // 0..63
    const int k4 = (i4 & 511) << 2;                  // 0..2044
    const float4 v = *(const float4*)&W[e * D_DIM + k4];
    Wt[(k4 + 0) * E_NUM + e] = v.x;
    Wt[(k4 + 1) * E_NUM + e] = v.y;
    Wt[(k4 + 2) * E_NUM + e] = v.z;
    Wt[(k4 + 3) * E_NUM + e] = v.w;
}

// block = 1024 threads = 16 waves; block owns 64 tokens (lane = token).
// wave w: k-half h = w>>3, experts [8*(w&7), +8).
// R8 lesson: the scalar (s_load) W path caps at ~85-100us — the single scalar
// pipe serves ~25cyc/64B req and 16 lockstep waves queue on it (R4->R8: 4x
// fewer reqs gave only 1.26x). W must use the VECTOR path (TCP: ~1 req/cyc).
// R5-R7 lesson: with 36.9KB LDS the backend sees "2 blocks/CU feasible",
// targets 8 waves/EU -> 64-VGPR budget -> re-rolls the 16-deep W load batch
// into issue-wait-consume pairs (VALUBusy 17%). Attributes cannot raise it.
// Fix: declare LDS > 80KB so 2 blocks/CU is architecturally impossible ->
// heuristic's own bound = 16 waves/CU = 4 waves/EU -> 128-VGPR budget.
// Grid is 256 = 1 block/CU, so this costs NOTHING. Demand ~111 < 128:
// 16 in-flight W float4 (64) + accd (16) + accc (8) + xr/addr (~23).
// R4 lesson (kept): vz asm-zero keeps W addressing on the vector path
// (readfirstlane scalarized it onto the scalar pipe).
// LDS union (only first 9216 floats used; size is the occupancy forcer):
//   gemm phase: xs(h,buf) at (h*2+buf)*2304, [64 rows][36]
//   epilogue:   S(h) at h*4096 + t*64 + e  (after last loop barrier, xs dead)
//   reduction:  pacc [0..256), cacc [256..512)
__global__ __launch_bounds__(1024) void fused_kernel(
    const float* __restrict__ x, const float* __restrict__ Wt,
    float* __restrict__ out, float* __restrict__ gprob, float* __restrict__ gcnt)
{
    __shared__ float lds[LDS_FLOATS];   // 82944 B

    const int tid  = threadIdx.x;
    const int wid  = tid >> 6;
    const int lane = tid & 63;           // token within block
    const int h    = wid >> 3;           // k-half
    const int eb   = (wid & 7) << 3;     // expert base (8 experts/wave)
    const long tok0 = (long)blockIdx.x * 64;

    // VGPR-held zero the compiler cannot fold: keeps W addressing divergent
    // -> global_load_dwordx4 (vector path), not s_load (scalar path).
    int vz;
    asm volatile("v_mov_b32 %0, 0" : "=v"(vz));
    const float* wbase = Wt + vz;

    // staging role: threads 0..511 stage half 0, 512..1023 stage half 1;
    // one float4 per thread per tile (64 rows x 32 k per half)
    const int sh   = tid >> 9;
    const int ss   = tid & 511;
    const int srow = ss >> 3;            // token row 0..63
    const int sc   = (ss & 7) << 2;      // k offset 0,4,...,28
    const float* xsrc = x + (tok0 + srow) * D_DIM + (sh << 10) + sc;

    double accd[8];
    #pragma unroll
    for (int e = 0; e < 8; ++e) accd[e] = 0.0;

    // ---- prologue: stage tile 0 ----
    float4 v0 = *(const float4*)(xsrc);
    *(float4*)&lds[(sh * 2) * XS_TILE + srow * XS_ROW + sc] = v0;
    __syncthreads();

    for (int it = 0; it < 32; ++it) {
        // issue next tile's global load early (HBM latency hides under compute)
        if (it < 31) v0 = *(const float4*)(xsrc + (it + 1) * BK);
        // ---- compute tile it from buf (it&1) ----
        const float* xb = lds + (h * 2 + (it & 1)) * XS_TILE + lane * XS_ROW;
        const int kb0 = (h << 10) + it * BK;
        #pragma unroll 1
        for (int c2 = 0; c2 < 2; ++c2) {     // two 16-k chunks (fold granularity)
            float accc[8];
            #pragma unroll
            for (int e = 0; e < 8; ++e) accc[e] = 0.0f;
            const float* xc = xb + c2 * 16;
            const float* wp = wbase + (size_t)(kb0 + c2 * 16) * E_NUM + eb;
            #pragma unroll 1
            for (int q = 0; q < 2; ++q) {    // 8-k batches bound W in flight
                const float4 xa  = *(const float4*)(xc + q * 8);
                const float4 xs4 = *(const float4*)(xc + q * 8 + 4);
                const float xr[8] = { xa.x, xa.y, xa.z, xa.w,
                                      xs4.x, xs4.y, xs4.z, xs4.w };
                float4 w0[8], w1[8];         // 16 float4 in flight (64 VGPR)
                #pragma unroll
                for (int k2 = 0; k2 < 8; ++k2) {
                    const float* wr = wp + (q * 8 + k2) * E_NUM;
                    w0[k2] = *(const float4*)(wr + 0);
                    w1[k2] = *(const float4*)(wr + 4);
                }
                // per-expert k ascending: q outer, k2 inner -> k 0..15 in order
                #pragma unroll
                for (int k2 = 0; k2 < 8; ++k2) {
                    const float xk = xr[k2];
                    accc[0] += xk * w0[k2].x;  accc[1] += xk * w0[k2].y;
                    accc[2] += xk * w0[k2].z;  accc[3] += xk * w0[k2].w;
                    accc[4] += xk * w1[k2].x;  accc[5] += xk * w1[k2].y;
                    accc[6] += xk * w1[k2].z;  accc[7] += xk * w1[k2].w;
                }
            }
            #pragma unroll
            for (int e = 0; e < 8; ++e) accd[e] += (double)accc[e];
        }
        // ---- write staged reg into the other buffer ----
        if (it < 31)
            *(float4*)&lds[(sh * 2 + ((it + 1) & 1)) * XS_TILE + srow * XS_ROW + sc] = v0;
        __syncthreads();
    }

    // ---- S overlay: per-half f32 partial logits (same split/cast as before) ----
    {
        float* sp = lds + h * 4096 + lane * 64 + eb;
        *(float4*)(sp + 0) = make_float4((float)accd[0], (float)accd[1],
                                         (float)accd[2], (float)accd[3]);
        *(float4*)(sp + 4) = make_float4((float)accd[4], (float)accd[5],
                                         (float)accd[6], (float)accd[7]);
    }
    __syncthreads();

    // ---- fused topk/softmax (waves 0..3; lane = expert; verbatim math) ----
    float pacc = 0.0f, cacc = 0.0f;
    if (wid < 4) {
        const int q = wid;
        for (int i = 0; i < 16; ++i) {
            const int  tl = q * 16 + i;
            const long t  = tok0 + tl;
            const float l = lds[tl * 64 + lane] + lds[4096 + tl * 64 + lane];
            // top-1 (max, lowest index on tie — matches jax.lax.top_k)
            float m1 = l; int i1 = lane;
            #pragma unroll
            for (int off = 32; off > 0; off >>= 1) {
                const float ov = __shfl_xor(m1, off, 64);
                const int   oi = __shfl_xor(i1, off, 64);
                if (ov > m1 || (ov == m1 && oi < i1)) { m1 = ov; i1 = oi; }
            }
            // full softmax prob for aux loss
            const float p = __expf(l - m1);
            float s = p;
            #pragma unroll
            for (int off = 32; off > 0; off >>= 1) s += __shfl_xor(s, off, 64);
            pacc += p / s;
            if (lane == i1) cacc += 1.0f;
            // top-2
            const float lm = (lane == i1) ? -1e30f : l;
            float m2 = lm; int i2 = lane;
            #pragma unroll
            for (int off = 32; off > 0; off >>= 1) {
                const float ov = __shfl_xor(m2, off, 64);
                const int   oi = __shfl_xor(i2, off, 64);
                if (ov > m2 || (ov == m2 && oi < i2)) { m2 = ov; i2 = oi; }
            }
            if (lane == 0) {
                out[2 * t]     = (float)i1;
                out[2 * t + 1] = (float)i2;
                const float w1 = 1.0f / (1.0f + __expf(m2 - m1));
                out[2 * M_TOK + 2 * t]     = w1;
                out[2 * M_TOK + 2 * t + 1] = 1.0f - w1;
            }
        }
    }
    __syncthreads();
    if (wid < 4) {
        lds[wid * 64 + lane]       = pacc;
        lds[256 + wid * 64 + lane] = cacc;
    }
    __syncthreads();
    if (wid == 0) {
        // same left-assoc 4-wave combine + one atomic per expert per 64-token block
        atomicAdd(&gprob[lane], lds[lane] + lds[64 + lane] + lds[128 + lane] + lds[192 + lane]);
        atomicAdd(&gcnt[lane],  lds[256 + lane] + lds[320 + lane] + lds[384 + lane] + lds[448 + lane]);
    }
}

__global__ __launch_bounds__(64) void aux_kernel(
    const float* __restrict__ gprob, const float* __restrict__ gcnt,
    float* __restrict__ out)
{
    const int lane = threadIdx.x;
    float v = gprob[lane] * gcnt[lane];
    #pragma unroll
    for (int off = 32; off > 0; off >>= 1) v += __shfl_xor(v, off, 64);
    if (lane == 0)
        out[4 * M_TOK] = 64.0f * 0.01f * v / ((float)M_TOK * (float)M_TOK);
}

extern "C" void kernel_launch(void* const* d_in, const int* in_sizes, int n_in,
                              void* d_out, int out_size, void* d_ws, size_t ws_size,
                              hipStream_t stream)
{
    const float* x = (const float*)d_in[0];
    const float* W = (const float*)d_in[1];
    float* out   = (float*)d_out;
    float* gprob = (float*)d_ws;
    float* gcnt  = gprob + 64;
    float* Wt    = gprob + 128;

    wt_kernel<<<128, 256, 0, stream>>>(W, Wt, gprob);
    fused_kernel<<<256, 1024, 0, stream>>>(x, Wt, out, gprob, gcnt);
    aux_kernel<<<1, 64, 0, stream>>>(gprob, gcnt, out);
}

// Round 10
// 287.717 us; speedup vs baseline: 1.4867x; 1.4867x over previous
//
#include <hip/hip_runtime.h>

typedef float f32x16 __attribute__((ext_vector_type(16)));

#define D_DIM 2048
#define E_NUM 64
#define M_TOK 16384          // B*L = 4*4096
#define BK 32                // k per staged tile
#define XS_ROW 36            // 32 + 4 pad: 144B rows keep 16B alignment for b128
#define XS_TILE (64 * XS_ROW)   // 2304 floats per (half, buf)

// ws layout: gprob[64], gcnt[64], pad to 512B, Wg[2][8][1024][8] f32 (512 KB)
// Wg[h][g][kk][e'] = W[g*8+e'][h*1024+kk]: each wave's W stream is LINEAR.

// one-off shuffle W[e][k] -> Wg via LDS transpose: coalesced reads AND writes
// (old version's scattered 4B stores serialized 64 lines per wave-store).
// grid 16 = 2 halves x 8 groups; block 0 also zeroes gprob/gcnt.
__global__ __launch_bounds__(256) void wg_kernel(const float* __restrict__ W,
                                                 float* __restrict__ Wg,
                                                 float* __restrict__ g) {
    __shared__ float t[8][1025];   // +1 pad: bank = (e+kk)%32, conflict-free
    const int b  = blockIdx.x;     // slab = h*8 + g
    const int h  = b >> 3, gq = b & 7;
    const int tid = threadIdx.x;
    if (b == 0 && tid < 128) g[tid] = 0.0f;
    #pragma unroll
    for (int p = 0; p < 8; ++p) {  // read 8 experts x 1024 k, coalesced float4
        const int e  = tid >> 5;
        const int k4 = ((tid & 31) << 2) + p * 128;
        const float4 v = *(const float4*)&W[(size_t)(gq * 8 + e) * D_DIM + h * 1024 + k4];
        t[e][k4 + 0] = v.x; t[e][k4 + 1] = v.y;
        t[e][k4 + 2] = v.z; t[e][k4 + 3] = v.w;
    }
    __syncthreads();
    float* dst = Wg + (size_t)b * 8192;
    #pragma unroll
    for (int p = 0; p < 8; ++p) {  // write [kk][e'] linear, coalesced float4
        const int off = p * 1024 + tid * 4;
        const int kk = off >> 3, e0 = off & 7;   // e0 in {0,4}
        float4 v;
        v.x = t[e0 + 0][kk]; v.y = t[e0 + 1][kk];
        v.z = t[e0 + 2][kk]; v.w = t[e0 + 3][kk];
        *(float4*)&dst[off] = v;
    }
}

// block = 1024 threads = 16 waves; block owns 64 tokens (lane = token).
// wave w: k-half h = w>>3, expert group g = w&7 (8 experts).
// R5-R9 lessons: 16-wave blocks are hard-capped at 64 VGPR (attributes and
// LDS forcing both falsified) -> vector-path W impossible; scalar path (W in
// SGPRs via s_load_dwordx16, VGPR=28) is the right structure. R8's limiter:
// per-batch lgkmcnt stalls (~250cyc L2 latency; R4 vs R8 shows pipe can do
// >=1 req/11cyc, R8 ran at 1/35cyc -> latency-, not throughput-bound).
// This version SOFTWARE-PIPELINES the linear W stream: prefetch next 32-float
// sub-batch (2 x s_load_dwordx16 = 32 SGPR) while FMA-ing current (32 FMA).
// Live: cur 32 + next 32 + addr ~20 < 102 SGPR file.
// LDS union (9216 floats):
//   gemm phase: xs(h,buf) at (h*2+buf)*2304, [64 rows][36]
//   epilogue:   S(h) at h*4096 + t*64 + e  (after last loop barrier, xs dead)
//   reduction:  pacc [0..256), cacc [256..512)
__global__ __launch_bounds__(1024) void fused_kernel(
    const float* __restrict__ x, const float* __restrict__ Wg,
    float* __restrict__ out, float* __restrict__ gprob, float* __restrict__ gcnt)
{
    __shared__ float lds[4 * XS_TILE];   // 36864 B

    const int tid  = threadIdx.x;
    const int wid  = tid >> 6;
    const int lane = tid & 63;           // token within block
    const int h    = wid >> 3;           // k-half
    const int eb   = (wid & 7) << 3;     // expert base (8 experts/wave)
    const long tok0 = (long)blockIdx.x * 64;
    // wave-uniform float-offset of this wave's W slab (8192 floats): keep in
    // SGPR so Wg loads stay on the scalar pipe (wanted here)
    const int wslab = __builtin_amdgcn_readfirstlane(((h << 3) + (wid & 7)) * 8192);
    const f32x16* wq = (const f32x16*)(Wg + wslab);   // linear: 512 x16 slots

    // staging role: threads 0..511 stage half 0, 512..1023 stage half 1;
    // one float4 per thread per tile (64 rows x 32 k per half)
    const int sh   = tid >> 9;
    const int ss   = tid & 511;
    const int srow = ss >> 3;            // token row 0..63
    const int sc   = (ss & 7) << 2;      // k offset 0,4,...,28
    const float* xsrc = x + (tok0 + srow) * D_DIM + (sh << 10) + sc;

    double accd[8];
    #pragma unroll
    for (int e = 0; e < 8; ++e) accd[e] = 0.0;

    // ---- prologue: stage tile 0; preload W sub-batch 0 ----
    float4 v0 = *(const float4*)(xsrc);
    *(float4*)&lds[(sh * 2) * XS_TILE + srow * XS_ROW + sc] = v0;
    f32x16 wc0 = wq[0];
    f32x16 wc1 = wq[1];
    __syncthreads();

    for (int it = 0; it < 32; ++it) {
        // issue next tile's global load early (HBM latency hides under compute)
        if (it < 31) v0 = *(const float4*)(xsrc + (it + 1) * BK);
        // ---- compute tile it from buf (it&1) ----
        const float* xb = lds + (h * 2 + (it & 1)) * XS_TILE + lane * XS_ROW;
        #pragma unroll 1
        for (int c2 = 0; c2 < 2; ++c2) {     // two 16-k chunks (fold granularity)
            float accc[8];
            #pragma unroll
            for (int e = 0; e < 8; ++e) accc[e] = 0.0f;
            const float* xc = xb + c2 * 16;
            const int sb0 = it * 8 + c2 * 4;   // sub-batch base (4 k each)
            #pragma unroll 1
            for (int s = 0; s < 4; ++s) {
                // prefetch NEXT sub-batch while computing current
                const int nx = (sb0 + s + 1 < 256) ? (sb0 + s + 1) : 255;
                const f32x16 wn0 = wq[nx * 2];
                const f32x16 wn1 = wq[nx * 2 + 1];
                const float4 xa = *(const float4*)(xc + s * 4);
                // per-expert chain k-ascending (k = s*4 + 0..3): same bits
                #pragma unroll
                for (int e = 0; e < 8; ++e) {
                    float a = accc[e];
                    a += xa.x * wc0[e];
                    a += xa.y * wc0[8 + e];
                    a += xa.z * wc1[e];
                    a += xa.w * wc1[8 + e];
                    accc[e] = a;
                }
                wc0 = wn0; wc1 = wn1;
            }
            #pragma unroll
            for (int e = 0; e < 8; ++e) accd[e] += (double)accc[e];
        }
        // ---- write staged reg into the other buffer ----
        if (it < 31)
            *(float4*)&lds[(sh * 2 + ((it + 1) & 1)) * XS_TILE + srow * XS_ROW + sc] = v0;
        __syncthreads();
    }

    // ---- S overlay: per-half f32 partial logits (same split/cast as before) ----
    {
        float* sp = lds + h * 4096 + lane * 64 + eb;
        *(float4*)(sp + 0) = make_float4((float)accd[0], (float)accd[1],
                                         (float)accd[2], (float)accd[3]);
        *(float4*)(sp + 4) = make_float4((float)accd[4], (float)accd[5],
                                         (float)accd[6], (float)accd[7]);
    }
    __syncthreads();

    // ---- fused topk/softmax (waves 0..3; lane = expert; verbatim math) ----
    float pacc = 0.0f, cacc = 0.0f;
    if (wid < 4) {
        const int q = wid;
        for (int i = 0; i < 16; ++i) {
            const int  tl = q * 16 + i;
            const long t  = tok0 + tl;
            const float l = lds[tl * 64 + lane] + lds[4096 + tl * 64 + lane];
            // top-1 (max, lowest index on tie — matches jax.lax.top_k)
            float m1 = l; int i1 = lane;
            #pragma unroll
            for (int off = 32; off > 0; off >>= 1) {
                const float ov = __shfl_xor(m1, off, 64);
                const int   oi = __shfl_xor(i1, off, 64);
                if (ov > m1 || (ov == m1 && oi < i1)) { m1 = ov; i1 = oi; }
            }
            // full softmax prob for aux loss
            const float p = __expf(l - m1);
            float s = p;
            #pragma unroll
            for (int off = 32; off > 0; off >>= 1) s += __shfl_xor(s, off, 64);
            pacc += p / s;
            if (lane == i1) cacc += 1.0f;
            // top-2
            const float lm = (lane == i1) ? -1e30f : l;
            float m2 = lm; int i2 = lane;
            #pragma unroll
            for (int off = 32; off > 0; off >>= 1) {
                const float ov = __shfl_xor(m2, off, 64);
                const int   oi = __shfl_xor(i2, off, 64);
                if (ov > m2 || (ov == m2 && oi < i2)) { m2 = ov; i2 = oi; }
            }
            if (lane == 0) {
                out[2 * t]     = (float)i1;
                out[2 * t + 1] = (float)i2;
                const float w1 = 1.0f / (1.0f + __expf(m2 - m1));
                out[2 * M_TOK + 2 * t]     = w1;
                out[2 * M_TOK + 2 * t + 1] = 1.0f - w1;
            }
        }
    }
    __syncthreads();
    if (wid < 4) {
        lds[wid * 64 + lane]       = pacc;
        lds[256 + wid * 64 + lane] = cacc;
    }
    __syncthreads();
    if (wid == 0) {
        // same left-assoc 4-wave combine + one atomic per expert per 64-token block
        atomicAdd(&gprob[lane], lds[lane] + lds[64 + lane] + lds[128 + lane] + lds[192 + lane]);
        atomicAdd(&gcnt[lane],  lds[256 + lane] + lds[320 + lane] + lds[384 + lane] + lds[448 + lane]);
    }
}

__global__ __launch_bounds__(64) void aux_kernel(
    const float* __restrict__ gprob, const float* __restrict__ gcnt,
    float* __restrict__ out)
{
    const int lane = threadIdx.x;
    float v = gprob[lane] * gcnt[lane];
    #pragma unroll
    for (int off = 32; off > 0; off >>= 1) v += __shfl_xor(v, off, 64);
    if (lane == 0)
        out[4 * M_TOK] = 64.0f * 0.01f * v / ((float)M_TOK * (float)M_TOK);
}

extern "C" void kernel_launch(void* const* d_in, const int* in_sizes, int n_in,
                              void* d_out, int out_size, void* d_ws, size_t ws_size,
                              hipStream_t stream)
{
    const float* x = (const float*)d_in[0];
    const float* W = (const float*)d_in[1];
    float* out   = (float*)d_out;
    float* gprob = (float*)d_ws;
    float* gcnt  = gprob + 64;
    float* Wg    = gprob + 128;   // 512B offset, 64B-aligned for s_load_dwordx16

    wg_kernel<<<16, 256, 0, stream>>>(W, Wg, gprob);
    fused_kernel<<<256, 1024, 0, stream>>>(x, Wg, out, gprob, gcnt);
    aux_kernel<<<1, 64, 0, stream>>>(gprob, gcnt, out);
}

// Round 11
// 262.137 us; speedup vs baseline: 1.6318x; 1.0976x over previous
//
#include <hip/hip_runtime.h>

typedef float f32x16 __attribute__((ext_vector_type(16)));
typedef float v2f    __attribute__((ext_vector_type(2)));

#define D_DIM 2048
#define E_NUM 64
#define M_TOK 16384          // B*L = 4*4096
#define BK 32                // k per staged tile
#define XS_ROW 36            // 32 + 4 pad: 144B rows, 16B-aligned for b128
#define XS_TILE (64 * XS_ROW)   // 2304 floats per (half, buf)

// ws layout: gprob[64], gcnt[64], ticket@[128], pad, Wg at +192 floats (768B,
// 64B-aligned). Wg[h][g][kk][e'] = W[g*8+e'][h*1024+kk]: per-wave W stream is
// LINEAR -> s_load_dwordx16-mergeable.

// one-off shuffle W[e][k] -> Wg via LDS transpose (coalesced both sides);
// block 0 also zeroes gprob/gcnt/ticket. grid 16 = 2 halves x 8 groups.
__global__ __launch_bounds__(256) void wg_kernel(const float* __restrict__ W,
                                                 float* __restrict__ Wg,
                                                 float* __restrict__ g) {
    __shared__ float t[8][1025];   // +1 pad: conflict-free transpose
    const int b  = blockIdx.x;     // slab = h*8 + g
    const int h  = b >> 3, gq = b & 7;
    const int tid = threadIdx.x;
    if (b == 0 && tid < 136) g[tid] = 0.0f;
    #pragma unroll
    for (int p = 0; p < 8; ++p) {  // read 8 experts x 1024 k, coalesced float4
        const int e  = tid >> 5;
        const int k4 = ((tid & 31) << 2) + p * 128;
        const float4 v = *(const float4*)&W[(size_t)(gq * 8 + e) * D_DIM + h * 1024 + k4];
        t[e][k4 + 0] = v.x; t[e][k4 + 1] = v.y;
        t[e][k4 + 2] = v.z; t[e][k4 + 3] = v.w;
    }
    __syncthreads();
    float* dst = Wg + (size_t)b * 8192;
    #pragma unroll
    for (int p = 0; p < 8; ++p) {  // write [kk][e'] linear, coalesced float4
        const int off = p * 1024 + tid * 4;
        const int kk = off >> 3, e0 = off & 7;   // e0 in {0,4}
        float4 v;
        v.x = t[e0 + 0][kk]; v.y = t[e0 + 1][kk];
        v.z = t[e0 + 2][kk]; v.w = t[e0 + 3][kk];
        *(float4*)&dst[off] = v;
    }
}

// Per 4-k step: 16 pk-fma (experts paired 2-wide; per-expert chain k-ascending
// -> bit-identical to scalar order; chains are independent).
#define PKSTEP(XA, U0, U1)  do {                                              \
    const v2f xk0 = {(XA).x, (XA).x};                                         \
    const v2f xk1 = {(XA).y, (XA).y};                                         \
    const v2f xk2 = {(XA).z, (XA).z};                                         \
    const v2f xk3 = {(XA).w, (XA).w};                                         \
    _Pragma("unroll")                                                         \
    for (int p = 0; p < 4; ++p) {                                             \
        acc2[p] = __builtin_elementwise_fma(xk0,                              \
                    (v2f){(U0)[2*p],     (U0)[2*p + 1]},     acc2[p]);        \
        acc2[p] = __builtin_elementwise_fma(xk1,                              \
                    (v2f){(U0)[8 + 2*p], (U0)[8 + 2*p + 1]}, acc2[p]);        \
        acc2[p] = __builtin_elementwise_fma(xk2,                              \
                    (v2f){(U1)[2*p],     (U1)[2*p + 1]},     acc2[p]);        \
        acc2[p] = __builtin_elementwise_fma(xk3,                              \
                    (v2f){(U1)[8 + 2*p], (U1)[8 + 2*p + 1]}, acc2[p]);        \
    }                                                                         \
} while (0)

// block = 1024 threads = 16 waves; block owns 64 tokens (lane = token).
// wave w: k-half h = w>>3, expert group g = w&7 (8 experts).
// R8/R10 model: scalar pipe services ~1 line/20cyc (68us/CU for the 512KB W
// stream); VALU ~62us; R8 ran them unoverlapped (121us). R10's rotate-prefetch
// added 32 s_mov per 32 FMA -> regressed. This version:
// (1) A/B double-buffer with NO copies (alternation via register naming,
//     4-k granularity, 2 s_load_dwordx16 per buffer; WAR deps enforce order);
// (2) v_pk_fma_f32 via elementwise_fma on float2 expert-pairs (halves VALU
//     issue; scalarizes to identical code if unsupported);
// (3) aux loss fused via device-scope ticket (last block computes it).
__global__ __launch_bounds__(1024) void fused_kernel(
    const float* __restrict__ x, const float* __restrict__ Wg,
    float* __restrict__ out, float* __restrict__ gprob, float* __restrict__ gcnt,
    unsigned* __restrict__ ticket)
{
    __shared__ float lds[4 * XS_TILE];   // 36864 B

    const int tid  = threadIdx.x;
    const int wid  = tid >> 6;
    const int lane = tid & 63;           // token within block
    const int h    = wid >> 3;           // k-half
    const int eb   = (wid & 7) << 3;     // expert base (8 experts/wave)
    const long tok0 = (long)blockIdx.x * 64;
    // wave-uniform slab offset in SGPR: W loads stay on the scalar pipe
    const int wslab = __builtin_amdgcn_readfirstlane(((h << 3) + (wid & 7)) * 8192);
    const f32x16* wq = (const f32x16*)(Wg + wslab);   // 512 x16 slots, linear

    // staging role: threads 0..511 stage half 0, 512..1023 stage half 1
    const int sh   = tid >> 9;
    const int ss   = tid & 511;
    const int srow = ss >> 3;            // token row 0..63
    const int sc   = (ss & 7) << 2;      // k offset 0,4,...,28
    const float* xsrc = x + (tok0 + srow) * D_DIM + (sh << 10) + sc;

    double accd[8];
    #pragma unroll
    for (int e = 0; e < 8; ++e) accd[e] = 0.0;

    // ---- prologue: stage tile 0; preload W sub-batch 0 into A ----
    float4 v0 = *(const float4*)(xsrc);
    *(float4*)&lds[(sh * 2) * XS_TILE + srow * XS_ROW + sc] = v0;
    f32x16 a0 = wq[0], a1 = wq[1];
    __syncthreads();

    for (int it = 0; it < 32; ++it) {
        // issue next tile's x load early (HBM latency hides under compute)
        if (it < 31) v0 = *(const float4*)(xsrc + (it + 1) * BK);
        const float* xb = lds + (h * 2 + (it & 1)) * XS_TILE + lane * XS_ROW;
        #pragma unroll 1
        for (int c2 = 0; c2 < 2; ++c2) {     // two 16-k chunks (fold granularity)
            v2f acc2[4];
            #pragma unroll
            for (int p = 0; p < 4; ++p) acc2[p] = (v2f){0.0f, 0.0f};
            const float* xc = xb + c2 * 16;
            const int s0 = it * 8 + c2 * 4;  // 4-k sub-batch index (0..252)
            f32x16 b0, b1;
            // step 0: load B <- s0+1; compute A (s0)
            b0 = wq[(s0 + 1) * 2]; b1 = wq[(s0 + 1) * 2 + 1];
            { const float4 xa = *(const float4*)(xc + 0);  PKSTEP(xa, a0, a1); }
            // step 1: load A <- s0+2; compute B (s0+1)
            a0 = wq[(s0 + 2) * 2]; a1 = wq[(s0 + 2) * 2 + 1];
            { const float4 xa = *(const float4*)(xc + 4);  PKSTEP(xa, b0, b1); }
            // step 2: load B <- s0+3; compute A (s0+2)
            b0 = wq[(s0 + 3) * 2]; b1 = wq[(s0 + 3) * 2 + 1];
            { const float4 xa = *(const float4*)(xc + 8);  PKSTEP(xa, a0, a1); }
            // step 3: load A <- s0+4 (next chunk); compute B (s0+3)
            { const int sn = (s0 + 4 < 256) ? (s0 + 4) * 2 : 510;
              a0 = wq[sn]; a1 = wq[sn + 1]; }
            { const float4 xa = *(const float4*)(xc + 12); PKSTEP(xa, b0, b1); }
            // fold: e ascending, same 16-k f32 chunks as ever -> same bits
            #pragma unroll
            for (int p = 0; p < 4; ++p) {
                accd[2 * p]     += (double)acc2[p].x;
                accd[2 * p + 1] += (double)acc2[p].y;
            }
        }
        if (it < 31)
            *(float4*)&lds[(sh * 2 + ((it + 1) & 1)) * XS_TILE + srow * XS_ROW + sc] = v0;
        __syncthreads();
    }

    // ---- S overlay: per-half f32 partial logits (same split/cast as before) ----
    {
        float* sp = lds + h * 4096 + lane * 64 + eb;
        *(float4*)(sp + 0) = make_float4((float)accd[0], (float)accd[1],
                                         (float)accd[2], (float)accd[3]);
        *(float4*)(sp + 4) = make_float4((float)accd[4], (float)accd[5],
                                         (float)accd[6], (float)accd[7]);
    }
    __syncthreads();

    // ---- fused topk/softmax (waves 0..3; lane = expert; verbatim math) ----
    float pacc = 0.0f, cacc = 0.0f;
    if (wid < 4) {
        const int q = wid;
        for (int i = 0; i < 16; ++i) {
            const int  tl = q * 16 + i;
            const long t  = tok0 + tl;
            const float l = lds[tl * 64 + lane] + lds[4096 + tl * 64 + lane];
            // top-1 (max, lowest index on tie — matches jax.lax.top_k)
            float m1 = l; int i1 = lane;
            #pragma unroll
            for (int off = 32; off > 0; off >>= 1) {
                const float ov = __shfl_xor(m1, off, 64);
                const int   oi = __shfl_xor(i1, off, 64);
                if (ov > m1 || (ov == m1 && oi < i1)) { m1 = ov; i1 = oi; }
            }
            // full softmax prob for aux loss
            const float p = __expf(l - m1);
            float s = p;
            #pragma unroll
            for (int off = 32; off > 0; off >>= 1) s += __shfl_xor(s, off, 64);
            pacc += p / s;
            if (lane == i1) cacc += 1.0f;
            // top-2
            const float lm = (lane == i1) ? -1e30f : l;
            float m2 = lm; int i2 = lane;
            #pragma unroll
            for (int off = 32; off > 0; off >>= 1) {
                const float ov = __shfl_xor(m2, off, 64);
                const int   oi = __shfl_xor(i2, off, 64);
                if (ov > m2 || (ov == m2 && oi < i2)) { m2 = ov; i2 = oi; }
            }
            if (lane == 0) {
                out[2 * t]     = (float)i1;
                out[2 * t + 1] = (float)i2;
                const float w1 = 1.0f / (1.0f + __expf(m2 - m1));
                out[2 * M_TOK + 2 * t]     = w1;
                out[2 * M_TOK + 2 * t + 1] = 1.0f - w1;
            }
        }
    }
    __syncthreads();
    if (wid < 4) {
        lds[wid * 64 + lane]       = pacc;
        lds[256 + wid * 64 + lane] = cacc;
    }
    __syncthreads();
    if (wid == 0) {
        // same left-assoc 4-wave combine + one atomic per expert per block
        atomicAdd(&gprob[lane], lds[lane] + lds[64 + lane] + lds[128 + lane] + lds[192 + lane]);
        atomicAdd(&gcnt[lane],  lds[256 + lane] + lds[320 + lane] + lds[384 + lane] + lds[448 + lane]);
        // ---- fused aux: last block to arrive computes the loss ----
        unsigned tk = 0;
        if (lane == 0) {
            __threadfence();                       // order our atomics before ticket
            tk = atomicAdd(ticket, 1u);
        }
        tk = __shfl(tk, 0, 64);
        if (tk == 255u) {                          // all 256 blocks done
            __threadfence();
            const float gp = atomicAdd(&gprob[lane], 0.0f);  // coherent read
            const float gc = atomicAdd(&gcnt[lane],  0.0f);
            float v = gp * gc;
            #pragma unroll
            for (int off = 32; off > 0; off >>= 1) v += __shfl_xor(v, off, 64);
            if (lane == 0)
                out[4 * M_TOK] = 64.0f * 0.01f * v / ((float)M_TOK * (float)M_TOK);
        }
    }
}

extern "C" void kernel_launch(void* const* d_in, const int* in_sizes, int n_in,
                              void* d_out, int out_size, void* d_ws, size_t ws_size,
                              hipStream_t stream)
{
    const float* x = (const float*)d_in[0];
    const float* W = (const float*)d_in[1];
    float* out   = (float*)d_out;
    float* gprob = (float*)d_ws;
    float* gcnt  = gprob + 64;
    unsigned* ticket = (unsigned*)(gprob + 128);
    float* Wg    = gprob + 192;   // 768B offset, 64B-aligned for s_load_dwordx16

    wg_kernel<<<16, 256, 0, stream>>>(W, Wg, gprob);
    fused_kernel<<<256, 1024, 0, stream>>>(x, Wg, out, gprob, gcnt, ticket);
}